// Round 1
// 112.354 us; speedup vs baseline: 1.0612x; 1.0612x over previous
//
#include <hip/hip_runtime.h>
#include <hip/hip_bf16.h>
#include <math.h>

// CapsNet dynamic routing. R17 = R16 + fp16/dot2 data path.
// Theory (R16 counters: VALUBusy 46%, HBM 9%, conflicts ~0): Phase A is
// L2-BW-floored on the W stream (~589 KB/block from XCD L2 ~ 22 us floor),
// routing is VALU/unpack bound. fp16 halves W+u bytes (floor ~11 us),
// halves Phase-A VMEM + in-flight regs, and v_dot2_f32_f16 collapses
// Phase-A MACs (32 dot2/stage) and b-update rows (8 dot2/row vs 24 VALU).
// Accuracy IMPROVES: uhat f16 (2^-11 rel) vs bf16 (2^-8); ce stays bf16
// (exp range). Pre-pass converts W->[i][j][q][m'][n-pair] f16 and
// u->[b][i][n-pair] f16 into d_ws (7.7 MB; ws-size guarded).
// Geometry unchanged: block=(j, 2 batches), 1024 thr, grid 1280,
// LDS 80.9 KB -> 2 blocks/CU, __launch_bounds__(1024,8) pins VGPR<=32.
// Spill tripwire: WRITE_SIZE must stay ~160 KB.
//
// u: [256][1152][8] f32; weight: [1152][10][8][16] f32; out: [256][10][16] f32

#define IC 1152
#define OC 10
#define NB 256
#define TILE_DW (IC * 8)              // dwords per batch tile (f16-packed)

#define NW_DW (IC * OC * 64)          // 737280 dwords: W as f16 n-pairs
#define NU_DW (NB * IC * 4)           // 1179648 dwords: u as f16 n-pairs
#define WS_NEED ((size_t)(NW_DW + NU_DW) * 4)

typedef float v2f __attribute__((ext_vector_type(2)));
typedef _Float16 h2 __attribute__((ext_vector_type(2)));

#if defined(__has_builtin)
#if __has_builtin(__builtin_amdgcn_fdot2)
#define HAVE_FDOT2 1
#endif
#endif

__device__ __forceinline__ float fdot2f(unsigned w, unsigned uu, float c) {
    h2 a = *(h2*)&w, b = *(h2*)&uu;
#ifdef HAVE_FDOT2
    return __builtin_amdgcn_fdot2(a, b, c, false);
#else
    return c + (float)a.x * (float)b.x + (float)a.y * (float)b.y;
#endif
}
__device__ __forceinline__ v2f h_v2(unsigned w) {
    h2 h = *(h2*)&w;
    v2f r = {(float)h.x, (float)h.y};
    return r;
}
__device__ __forceinline__ unsigned packh2(float a, float b) {
    h2 h = {(_Float16)a, (_Float16)b};
    return *(unsigned*)&h;
}
__device__ __forceinline__ unsigned short pack1(float a) {
    __hip_bfloat16 h = __float2bfloat16(a);
    return *(unsigned short*)&h;
}

// ---- Pre-pass: W f32 -> f16 pairs along n, transposed; u f32 -> f16 pairs ----
// Wh dword e: k=e&3 (n-pair), mp=(e>>2)&3, q=(e>>4)&3, ij=e>>6; m=q*4+mp
//   value = pack(W[ij][2k][m], W[ij][2k+1][m])
// uh dword e: pr=e&3, bi=e>>2; value = pack(u[bi][2pr], u[bi][2pr+1])
__global__ void convert_kernel(const float* __restrict__ u,
                               const float* __restrict__ W,
                               unsigned* __restrict__ ws, int do_u) {
    const int tid = blockIdx.x * blockDim.x + threadIdx.x;
    if (tid < NW_DW) {
        const int k = tid & 3, mp = (tid >> 2) & 3, q = (tid >> 4) & 3, ij = tid >> 6;
        const int m = (q << 2) + mp;
        const float* s = W + ((size_t)ij << 7) + m + (k << 5);
        ws[tid] = packh2(s[0], s[16]);
    } else if (do_u) {
        const int e = tid - NW_DW;
        if (e < NU_DW) {
            const int pr = e & 3, bi = e >> 2;
            const float* s = u + ((size_t)bi << 3) + (pr << 1);
            ws[NW_DW + e] = packh2(s[0], s[1]);
        }
    }
}

template<bool UF16>
__global__ __launch_bounds__(1024, 8)
void caps_route_kernel(const float* __restrict__ u,
                       const unsigned* __restrict__ Wh,
                       const unsigned* __restrict__ ug,
                       float* __restrict__ out) {
    extern __shared__ unsigned smem_u[];
    unsigned* uh = smem_u;                                    // 2 tiles (73728 B)
    unsigned short* ce = (unsigned short*)(uh + 2 * TILE_DW); // [2 bt][IC] (4608 B)
    float* spart = (float*)(ce + 2 * IC);                     // [2 par][2 bt][8][20] (2560 B)

    const int t    = threadIdx.x;
    const int bx   = blockIdx.x;
    const int lane = t & 63;
    const int wid  = t >> 6;

    // XCD-aware (j, batch-pair) mapping (xcd = bx & 7 heuristic).
    int x = bx & 7, sg = bx >> 3;
    int j, p;
    if (sg < 128) { j = x; p = sg; }
    else { int s2 = sg - 128; j = 8 + (x >> 2); p = ((x & 3) << 5) + s2; }
    const int bb = p * 2;  // batches bb, bb+1

    // ---- Phase A: uhat[B][i][m] -> LDS f16, half-XOR swizzle; fdot2 MACs ----
    {
        const int q  = t & 3;
        const int i0 = t >> 2;           // 0..255
        const int pb = (((q >> 1) ^ ((i0 >> 2) & 1)) << 2) + ((q & 1) << 1);
        const float* u0p = u + (size_t)bb * (IC * 8);
        const uint4* ua4 = (const uint4*)ug + (size_t)bb * IC;
        const uint4* ub4 = ua4 + IC;

        auto stage = [&](int i) {
            const uint4* wq4 = (const uint4*)Wh + (((size_t)(i * OC + j) << 2) + q) * 4;
            uint4 Ua, Ub;
            if constexpr (UF16) {
                Ua = ua4[i];
                Ub = ub4[i];
            } else {
                const float4 a0 = *(const float4*)(u0p + i * 8);
                const float4 a1 = *(const float4*)(u0p + i * 8 + 4);
                const float4 b0 = *(const float4*)(u0p + IC * 8 + i * 8);
                const float4 b1 = *(const float4*)(u0p + IC * 8 + i * 8 + 4);
                Ua = make_uint4(packh2(a0.x, a0.y), packh2(a0.z, a0.w),
                                packh2(a1.x, a1.y), packh2(a1.z, a1.w));
                Ub = make_uint4(packh2(b0.x, b0.y), packh2(b0.z, b0.w),
                                packh2(b1.x, b1.y), packh2(b1.z, b1.w));
            }
            const uint4 w0 = wq4[0], w1 = wq4[1], w2 = wq4[2], w3 = wq4[3];
            float A0, A1, A2, A3, B0, B1, B2, B3;
#define DOT8(acc, wm) \
            acc = fdot2f(wm.x, Ua.x, 0.f);  acc = fdot2f(wm.y, Ua.y, acc); \
            acc = fdot2f(wm.z, Ua.z, acc);  acc = fdot2f(wm.w, Ua.w, acc);
#define DOT8B(acc, wm) \
            acc = fdot2f(wm.x, Ub.x, 0.f);  acc = fdot2f(wm.y, Ub.y, acc); \
            acc = fdot2f(wm.z, Ub.z, acc);  acc = fdot2f(wm.w, Ub.w, acc);
            DOT8(A0, w0) DOT8(A1, w1) DOT8(A2, w2) DOT8(A3, w3)
            DOT8B(B0, w0) DOT8B(B1, w1) DOT8B(B2, w2) DOT8B(B3, w3)
#undef DOT8
#undef DOT8B
            const int dst = (i << 3) + pb;
            *(uint2*)&uh[dst]           = make_uint2(packh2(A0, A1), packh2(A2, A3));
            *(uint2*)&uh[TILE_DW + dst] = make_uint2(packh2(B0, B1), packh2(B2, B3));
        };
#pragma unroll
        for (int k = 0; k < 4; ++k) stage(i0 + 256 * k);
        if (i0 < IC - 1024) stage(i0 + 1024);
    }

    __syncthreads();  // B0: uhat ready

    // ---- Routing: octet w8 of batch bt owns rows [w8*144, +144) ----
    const int bt = wid >> 3;
    const int w8 = wid & 7;
    const int rowbase = w8 * 144;      // 144 = 9*16, 144 mod 8 == 0 -> parity math valid
    const unsigned* uhT = uh + bt * TILE_DW;
    unsigned short* ceT = ce + bt * IC;

    const int mqc = lane & 3;
    const int h   = lane >> 2;
    const int pbS = (((mqc >> 1) ^ ((h >> 2) & 1)) << 2) + ((mqc & 1) << 1);
    const bool eB = ((lane >> 2) & 1) != 0;
    // dynamic-index broadcast sources (quad within width-4 group), eB-swapped
    const int sA0 = eB ? 2 : 0, sA1 = eB ? 3 : 1;
    const int sB0 = eB ? 0 : 2, sB1 = eB ? 1 : 3;

    float L[3];
#pragma unroll
    for (int k = 0; k < 3; ++k) L[k] = 0.f;
    float se = 0.f;
    float4 vq;

    for (int r = 0; r < 3; ++r) {
        // ---- s-pass over own 144 rows (c from ce for r>0; same-wave LDS) ----
        v2f aA = {0.f, 0.f}, aB = {0.f, 0.f};
        if (r == 0) {
#pragma unroll 3
            for (int k = 0; k < 9; ++k) {
                const int i = rowbase + 16 * k + h;
                const uint2 d = *(const uint2*)&uhT[(i << 3) + pbS];
                aA += h_v2(d.x);
                aB += h_v2(d.y);
            }
        } else {
#pragma unroll 3
            for (int k = 0; k < 9; ++k) {
                const int i = rowbase + 16 * k + h;
                const uint2 d = *(const uint2*)&uhT[(i << 3) + pbS];
                const float c = __uint_as_float(((unsigned)ceT[i]) << 16);
                const v2f cs = {c, c};
                aA += cs * h_v2(d.x);
                aB += cs * h_v2(d.y);
            }
        }
        float4 acc = make_float4(aA.x, aA.y, aB.x, aB.y);
#pragma unroll
        for (int o = 4; o <= 32; o <<= 1) {   // reduce over h within wave
            acc.x += __shfl_xor(acc.x, o, 64); acc.y += __shfl_xor(acc.y, o, 64);
            acc.z += __shfl_xor(acc.z, o, 64); acc.w += __shfl_xor(acc.w, o, 64);
        }
        float* spR = spart + (r & 1) * 320 + bt * 160;
        if (lane < 4) *(float4*)&spR[w8 * 20 + (lane << 2)] = acc;
        else if (r > 0 && lane == 4) spR[w8 * 20 + 16] = se;
        __syncthreads();  // B(r+1)

        // ---- combine all 8 octet partials + squash -> vq ----
        {
            float4 ss = {0.f, 0.f, 0.f, 0.f};
            float sesum = 0.f;
#pragma unroll
            for (int s8 = 0; s8 < 8; ++s8) {
                const float4 qq = *(const float4*)&spR[s8 * 20 + (mqc << 2)];
                ss.x += qq.x; ss.y += qq.y; ss.z += qq.z; ss.w += qq.w;
                sesum += spR[s8 * 20 + 16];
            }
            const float inv = (r == 0) ? (1.0f / (float)IC) : 1.0f / sesum;
            const float4 s4 = make_float4(ss.x * inv, ss.y * inv, ss.z * inv, ss.w * inv);
            float p2 = s4.x*s4.x + s4.y*s4.y + s4.z*s4.z + s4.w*s4.w;
            p2 += __shfl_xor(p2, 1, 64);
            p2 += __shfl_xor(p2, 2, 64);   // sum over mq quads
            const float sc = p2 / ((1.0f + p2) * sqrtf(p2 + 1e-8f));
            vq = make_float4(s4.x * sc, s4.y * sc, s4.z * sc, s4.w * sc);
        }

        if (r == 2) {
            if (w8 == 0 && lane < 4)
                *(float4*)&out[((size_t)(bb + bt) * OC + j) * 16 + (lane << 2)] = vq;
        } else {
            // ---- b-update fused with exp; v packed f16, dot2 rows ----
            const unsigned p01 = packh2(vq.x, vq.y), p23 = packh2(vq.z, vq.w);
            const unsigned vh0 = __shfl((int)p01, sA0, 4), vh1 = __shfl((int)p23, sA0, 4);
            const unsigned vh2 = __shfl((int)p01, sA1, 4), vh3 = __shfl((int)p23, sA1, 4);
            const unsigned vh4 = __shfl((int)p01, sB0, 4), vh5 = __shfl((int)p23, sB0, 4);
            const unsigned vh6 = __shfl((int)p01, sB1, 4), vh7 = __shfl((int)p23, sB1, 4);
            se = 0.f;
#define BROW(i, Lk) {                                                     \
            const uint4 da = *(const uint4*)&uhT[(i) << 3];               \
            const uint4 db = *(const uint4*)&uhT[((i) << 3) + 4];         \
            float dpA = fdot2f(da.x, vh0, 0.f);                           \
            dpA = fdot2f(da.y, vh1, dpA);                                 \
            dpA = fdot2f(da.z, vh2, dpA);                                 \
            dpA = fdot2f(da.w, vh3, dpA);                                 \
            float dpB = fdot2f(db.x, vh4, 0.f);                           \
            dpB = fdot2f(db.y, vh5, dpB);                                 \
            dpB = fdot2f(db.z, vh6, dpB);                                 \
            dpB = fdot2f(db.w, vh7, dpB);                                 \
            Lk += dpA + dpB;                                              \
            const float ev = __expf(Lk);  /* max-free: verified R6-R15 */ \
            ceT[i] = pack1(ev);                                           \
            se += ev; }
            BROW(rowbase + lane, L[0])
            BROW(rowbase + lane + 64, L[1])
            if (lane < 16) { BROW(rowbase + 128 + lane, L[2]) }
#undef BROW
#pragma unroll
            for (int o = 32; o >= 1; o >>= 1) se += __shfl_xor(se, o, 64);
        }
    }
}

extern "C" void kernel_launch(void* const* d_in, const int* in_sizes, int n_in,
                              void* d_out, int out_size, void* d_ws, size_t ws_size,
                              hipStream_t stream) {
    const float* u = (const float*)d_in[0];
    const float* W = (const float*)d_in[1];
    float* out = (float*)d_out;
    unsigned* ws = (unsigned*)d_ws;

    const int do_u = (ws_size >= WS_NEED) ? 1 : 0;
    const int total = NW_DW + (do_u ? NU_DW : 0);
    convert_kernel<<<(total + 255) / 256, 256, 0, stream>>>(u, W, ws, do_u);

    const size_t shmem = (size_t)2 * TILE_DW * 4   // two batch tiles (f16)
                       + (size_t)2 * IC * 2        // ce
                       + 640 * 4;                  // spart => 80896 B (x2 <= 160 KiB pool)
    if (do_u) {
        hipFuncSetAttribute((const void*)caps_route_kernel<true>,
                            hipFuncAttributeMaxDynamicSharedMemorySize, (int)shmem);
        caps_route_kernel<true><<<(NB / 2) * OC, 1024, shmem, stream>>>(u, ws, ws + NW_DW, out);
    } else {
        hipFuncSetAttribute((const void*)caps_route_kernel<false>,
                            hipFuncAttributeMaxDynamicSharedMemorySize, (int)shmem);
        caps_route_kernel<false><<<(NB / 2) * OC, 1024, shmem, stream>>>(u, ws, ws + NW_DW, out);
    }
}

// Round 2
// 111.651 us; speedup vs baseline: 1.0679x; 1.0063x over previous
//
#include <hip/hip_runtime.h>
#include <hip/hip_bf16.h>
#include <math.h>

// CapsNet dynamic routing. R18 = R17 + r=0 s-pass folded into Phase A.
// Theory (R17 counters: VALUBusy 56%, HBM 5.5%, conflicts ~0): routing is
// VALU/LDS-chain bound; Phase A is L2-BW-floored (~11 us) with idle VALU.
// At r=0 softmax(0) is uniform -> s = (sum_i uhat)/1152, and Phase A holds
// every uhat in registers. So: accumulate packed-f16 column sums during
// Phase A (4 v_pk_add_f16/stage, +4 VGPR), shfl-reduce, stash 16-wave
// partials in LDS (overlaid on spart parity-0; disjoint lifetime), and make
// round 0 combine-only. Removes r=0's 9-iter LDS s-pass + 32-op reduce +
// one full barrier round (4 -> 3 syncthreads).
// Phase A stage restructured to pairwise W loads to hold the 32-VGPR wall.
// Tripwires: VGPR 32, WRITE_SIZE ~160 KB (spill), absmax < ~0.008.
// Geometry unchanged: block=(j, 2 batches), 1024 thr, grid 1280,
// LDS 80.9 KB -> 2 blocks/CU, __launch_bounds__(1024,8).
//
// u: [256][1152][8] f32; weight: [1152][10][8][16] f32; out: [256][10][16] f32

#define IC 1152
#define OC 10
#define NB 256
#define TILE_DW (IC * 8)              // dwords per batch tile (f16-packed)

#define NW_DW (IC * OC * 64)          // 737280 dwords: W as f16 n-pairs
#define NU_DW (NB * IC * 4)           // 1179648 dwords: u as f16 n-pairs
#define WS_NEED ((size_t)(NW_DW + NU_DW) * 4)

typedef float v2f __attribute__((ext_vector_type(2)));
typedef _Float16 h2 __attribute__((ext_vector_type(2)));

#if defined(__has_builtin)
#if __has_builtin(__builtin_amdgcn_fdot2)
#define HAVE_FDOT2 1
#endif
#endif

__device__ __forceinline__ float fdot2f(unsigned w, unsigned uu, float c) {
    h2 a = *(h2*)&w, b = *(h2*)&uu;
#ifdef HAVE_FDOT2
    return __builtin_amdgcn_fdot2(a, b, c, false);
#else
    return c + (float)a.x * (float)b.x + (float)a.y * (float)b.y;
#endif
}
__device__ __forceinline__ v2f h_v2(unsigned w) {
    h2 h = *(h2*)&w;
    v2f r = {(float)h.x, (float)h.y};
    return r;
}
__device__ __forceinline__ unsigned packh2(float a, float b) {
    h2 h = {(_Float16)a, (_Float16)b};
    return *(unsigned*)&h;
}
__device__ __forceinline__ unsigned short pack1(float a) {
    __hip_bfloat16 h = __float2bfloat16(a);
    return *(unsigned short*)&h;
}
__device__ __forceinline__ unsigned h2bits(h2 v) { return *(unsigned*)&v; }
__device__ __forceinline__ h2 h2shfl_add(h2 v, int o) {
    unsigned b = h2bits(v);
    unsigned s = (unsigned)__shfl_xor((int)b, o, 64);
    return v + *(h2*)&s;
}

// ---- Pre-pass: W f32 -> f16 pairs along n, transposed; u f32 -> f16 pairs ----
__global__ void convert_kernel(const float* __restrict__ u,
                               const float* __restrict__ W,
                               unsigned* __restrict__ ws, int do_u) {
    const int tid = blockIdx.x * blockDim.x + threadIdx.x;
    if (tid < NW_DW) {
        const int k = tid & 3, mp = (tid >> 2) & 3, q = (tid >> 4) & 3, ij = tid >> 6;
        const int m = (q << 2) + mp;
        const float* s = W + ((size_t)ij << 7) + m + (k << 5);
        ws[tid] = packh2(s[0], s[16]);
    } else if (do_u) {
        const int e = tid - NW_DW;
        if (e < NU_DW) {
            const int pr = e & 3, bi = e >> 2;
            const float* s = u + ((size_t)bi << 3) + (pr << 1);
            ws[NW_DW + e] = packh2(s[0], s[1]);
        }
    }
}

template<bool UF16>
__global__ __launch_bounds__(1024, 8)
void caps_route_kernel(const float* __restrict__ u,
                       const unsigned* __restrict__ Wh,
                       const unsigned* __restrict__ ug,
                       float* __restrict__ out) {
    extern __shared__ unsigned smem_u[];
    unsigned* uh = smem_u;                                    // 2 tiles (73728 B)
    unsigned short* ce = (unsigned short*)(uh + 2 * TILE_DW); // [2 bt][IC] (4608 B)
    float* spart = (float*)(ce + 2 * IC);                     // [2 par][2 bt][8][20] (2560 B)
    // r0 partials overlay spart parity-0: [2 bt][16 wid][8 dw] f16 (1024 B).
    unsigned* r0p = (unsigned*)spart;

    const int t    = threadIdx.x;
    const int bx   = blockIdx.x;
    const int lane = t & 63;
    const int wid  = t >> 6;

    // XCD-aware (j, batch-pair) mapping (xcd = bx & 7 heuristic).
    int x = bx & 7, sg = bx >> 3;
    int j, p;
    if (sg < 128) { j = x; p = sg; }
    else { int s2 = sg - 128; j = 8 + (x >> 2); p = ((x & 3) << 5) + s2; }
    const int bb = p * 2;  // batches bb, bb+1

    // ---- Phase A: uhat -> LDS f16 (half-XOR swizzle) + r0 column sums ----
    {
        const int q  = t & 3;
        const int i0 = t >> 2;           // 0..255
        const int pb = (((q >> 1) ^ ((i0 >> 2) & 1)) << 2) + ((q & 1) << 1);
        const float* u0p = u + (size_t)bb * (IC * 8);
        const uint4* ua4 = (const uint4*)ug + (size_t)bb * IC;
        const uint4* ub4 = ua4 + IC;

        h2 sA01 = {0.f, 0.f}, sA23 = {0.f, 0.f};
        h2 sB01 = {0.f, 0.f}, sB23 = {0.f, 0.f};

        auto stage = [&](int i) {
            const uint4* wq4 = (const uint4*)Wh + (((size_t)(i * OC + j) << 2) + q) * 4;
            uint4 Ua, Ub;
            if constexpr (UF16) {
                Ua = ua4[i];
                Ub = ub4[i];
            } else {
                const float4 a0 = *(const float4*)(u0p + i * 8);
                const float4 a1 = *(const float4*)(u0p + i * 8 + 4);
                const float4 b0 = *(const float4*)(u0p + IC * 8 + i * 8);
                const float4 b1 = *(const float4*)(u0p + IC * 8 + i * 8 + 4);
                Ua = make_uint4(packh2(a0.x, a0.y), packh2(a0.z, a0.w),
                                packh2(a1.x, a1.y), packh2(a1.z, a1.w));
                Ub = make_uint4(packh2(b0.x, b0.y), packh2(b0.z, b0.w),
                                packh2(b1.x, b1.y), packh2(b1.z, b1.w));
            }
#define DOT8(acc, wm, Um) \
            acc = fdot2f(wm.x, Um.x, 0.f);  acc = fdot2f(wm.y, Um.y, acc); \
            acc = fdot2f(wm.z, Um.z, acc);  acc = fdot2f(wm.w, Um.w, acc);
            // pairwise W loads to cap live VGPRs (32-reg wall)
            const uint4 w0 = wq4[0], w1 = wq4[1];
            float A0, A1, B0, B1;
            DOT8(A0, w0, Ua) DOT8(A1, w1, Ua)
            DOT8(B0, w0, Ub) DOT8(B1, w1, Ub)
            const unsigned pa01 = packh2(A0, A1), pb01 = packh2(B0, B1);
            const uint4 w2 = wq4[2], w3 = wq4[3];
            float A2, A3, B2, B3;
            DOT8(A2, w2, Ua) DOT8(A3, w3, Ua)
            DOT8(B2, w2, Ub) DOT8(B3, w3, Ub)
            const unsigned pa23 = packh2(A2, A3), pb23 = packh2(B2, B3);
#undef DOT8
            sA01 += *(const h2*)&pa01;  sA23 += *(const h2*)&pa23;
            sB01 += *(const h2*)&pb01;  sB23 += *(const h2*)&pb23;
            const int dst = (i << 3) + pb;
            *(uint2*)&uh[dst]           = make_uint2(pa01, pa23);
            *(uint2*)&uh[TILE_DW + dst] = make_uint2(pb01, pb23);
        };
#pragma unroll
        for (int k = 0; k < 4; ++k) stage(i0 + 256 * k);
        if (i0 < IC - 1024) stage(i0 + 1024);

        // reduce r0 sums across the 16 h-groups of the wave
#pragma unroll
        for (int o = 4; o <= 32; o <<= 1) {
            sA01 = h2shfl_add(sA01, o);  sA23 = h2shfl_add(sA23, o);
            sB01 = h2shfl_add(sB01, o);  sB23 = h2shfl_add(sB23, o);
        }
        if (lane < 4) {   // lane == q for lanes 0..3
            *(uint2*)&r0p[wid * 8 + (lane << 1)]       = make_uint2(h2bits(sA01), h2bits(sA23));
            *(uint2*)&r0p[128 + wid * 8 + (lane << 1)] = make_uint2(h2bits(sB01), h2bits(sB23));
        }
    }

    __syncthreads();  // B0: uhat + r0 partials ready

    // ---- Routing: octet w8 of batch bt owns rows [w8*144, +144) ----
    const int bt = wid >> 3;
    const int w8 = wid & 7;
    const int rowbase = w8 * 144;      // 144 = 9*16, 144 mod 8 == 0 -> parity math valid
    const unsigned* uhT = uh + bt * TILE_DW;
    unsigned short* ceT = ce + bt * IC;

    const int mqc = lane & 3;
    const int h   = lane >> 2;
    const int pbS = (((mqc >> 1) ^ ((h >> 2) & 1)) << 2) + ((mqc & 1) << 1);
    const bool eB = ((lane >> 2) & 1) != 0;
    // dynamic-index broadcast sources (quad within width-4 group), eB-swapped
    const int sA0 = eB ? 2 : 0, sA1 = eB ? 3 : 1;
    const int sB0 = eB ? 0 : 2, sB1 = eB ? 1 : 3;

    float L[3];
#pragma unroll
    for (int k = 0; k < 3; ++k) L[k] = 0.f;
    float se = 0.f;
    float4 vq;

    auto bupdate = [&](const float4 v4) {
        // b-update fused with exp; v packed f16, dot2 rows
        const unsigned p01 = packh2(v4.x, v4.y), p23 = packh2(v4.z, v4.w);
        const unsigned vh0 = __shfl((int)p01, sA0, 4), vh1 = __shfl((int)p23, sA0, 4);
        const unsigned vh2 = __shfl((int)p01, sA1, 4), vh3 = __shfl((int)p23, sA1, 4);
        const unsigned vh4 = __shfl((int)p01, sB0, 4), vh5 = __shfl((int)p23, sB0, 4);
        const unsigned vh6 = __shfl((int)p01, sB1, 4), vh7 = __shfl((int)p23, sB1, 4);
        se = 0.f;
#define BROW(i, Lk) {                                                     \
        const uint4 da = *(const uint4*)&uhT[(i) << 3];                   \
        const uint4 db = *(const uint4*)&uhT[((i) << 3) + 4];             \
        float dpA = fdot2f(da.x, vh0, 0.f);                               \
        dpA = fdot2f(da.y, vh1, dpA);                                     \
        dpA = fdot2f(da.z, vh2, dpA);                                     \
        dpA = fdot2f(da.w, vh3, dpA);                                     \
        float dpB = fdot2f(db.x, vh4, 0.f);                               \
        dpB = fdot2f(db.y, vh5, dpB);                                     \
        dpB = fdot2f(db.z, vh6, dpB);                                     \
        dpB = fdot2f(db.w, vh7, dpB);                                     \
        Lk += dpA + dpB;                                                  \
        const float ev = __expf(Lk);  /* max-free: verified R6-R15 */     \
        ceT[i] = pack1(ev);                                               \
        se += ev; }
        BROW(rowbase + lane, L[0])
        BROW(rowbase + lane + 64, L[1])
        if (lane < 16) { BROW(rowbase + 128 + lane, L[2]) }
#undef BROW
#pragma unroll
        for (int o = 32; o >= 1; o >>= 1) se += __shfl_xor(se, o, 64);
    };

    // ---- Round 0: combine-only (c uniform; partials from Phase A) ----
    {
        h2 a01 = {0.f, 0.f}, a23 = {0.f, 0.f};
#pragma unroll
        for (int w = 0; w < 16; ++w) {
            const uint2 d = *(const uint2*)&r0p[bt * 128 + w * 8 + (mqc << 1)];
            a01 += *(const h2*)&d.x;
            a23 += *(const h2*)&d.y;
        }
        const float inv = 1.0f / (float)IC;
        const float4 s4 = make_float4((float)a01.x * inv, (float)a01.y * inv,
                                      (float)a23.x * inv, (float)a23.y * inv);
        float p2 = s4.x*s4.x + s4.y*s4.y + s4.z*s4.z + s4.w*s4.w;
        p2 += __shfl_xor(p2, 1, 64);
        p2 += __shfl_xor(p2, 2, 64);   // sum over mq quads
        const float sc = p2 / ((1.0f + p2) * sqrtf(p2 + 1e-8f));
        vq = make_float4(s4.x * sc, s4.y * sc, s4.z * sc, s4.w * sc);
    }
    bupdate(vq);

    // ---- Rounds 1,2 ----
    for (int r = 1; r < 3; ++r) {
        // s-pass over own 144 rows (c from ce; same-wave LDS, no barrier)
        v2f aA = {0.f, 0.f}, aB = {0.f, 0.f};
#pragma unroll 3
        for (int k = 0; k < 9; ++k) {
            const int i = rowbase + 16 * k + h;
            const uint2 d = *(const uint2*)&uhT[(i << 3) + pbS];
            const float c = __uint_as_float(((unsigned)ceT[i]) << 16);
            const v2f cs = {c, c};
            aA += cs * h_v2(d.x);
            aB += cs * h_v2(d.y);
        }
        float4 acc = make_float4(aA.x, aA.y, aB.x, aB.y);
#pragma unroll
        for (int o = 4; o <= 32; o <<= 1) {   // reduce over h within wave
            acc.x += __shfl_xor(acc.x, o, 64); acc.y += __shfl_xor(acc.y, o, 64);
            acc.z += __shfl_xor(acc.z, o, 64); acc.w += __shfl_xor(acc.w, o, 64);
        }
        float* spR = spart + (r & 1) * 320 + bt * 160;
        if (lane < 4) *(float4*)&spR[w8 * 20 + (lane << 2)] = acc;
        else if (lane == 4) spR[w8 * 20 + 16] = se;
        __syncthreads();  // B(r)

        // combine all 8 octet partials + squash -> vq
        {
            float4 ss = {0.f, 0.f, 0.f, 0.f};
            float sesum = 0.f;
#pragma unroll
            for (int s8 = 0; s8 < 8; ++s8) {
                const float4 qq = *(const float4*)&spR[s8 * 20 + (mqc << 2)];
                ss.x += qq.x; ss.y += qq.y; ss.z += qq.z; ss.w += qq.w;
                sesum += spR[s8 * 20 + 16];
            }
            const float inv = 1.0f / sesum;
            const float4 s4 = make_float4(ss.x * inv, ss.y * inv, ss.z * inv, ss.w * inv);
            float p2 = s4.x*s4.x + s4.y*s4.y + s4.z*s4.z + s4.w*s4.w;
            p2 += __shfl_xor(p2, 1, 64);
            p2 += __shfl_xor(p2, 2, 64);   // sum over mq quads
            const float sc = p2 / ((1.0f + p2) * sqrtf(p2 + 1e-8f));
            vq = make_float4(s4.x * sc, s4.y * sc, s4.z * sc, s4.w * sc);
        }

        if (r == 2) {
            if (w8 == 0 && lane < 4)
                *(float4*)&out[((size_t)(bb + bt) * OC + j) * 16 + (lane << 2)] = vq;
        } else {
            bupdate(vq);
        }
    }
}

extern "C" void kernel_launch(void* const* d_in, const int* in_sizes, int n_in,
                              void* d_out, int out_size, void* d_ws, size_t ws_size,
                              hipStream_t stream) {
    const float* u = (const float*)d_in[0];
    const float* W = (const float*)d_in[1];
    float* out = (float*)d_out;
    unsigned* ws = (unsigned*)d_ws;

    const int do_u = (ws_size >= WS_NEED) ? 1 : 0;
    const int total = NW_DW + (do_u ? NU_DW : 0);
    convert_kernel<<<(total + 255) / 256, 256, 0, stream>>>(u, W, ws, do_u);

    const size_t shmem = (size_t)2 * TILE_DW * 4   // two batch tiles (f16)
                       + (size_t)2 * IC * 2        // ce
                       + 640 * 4;                  // spart (r0p overlays parity 0)
    if (do_u) {
        hipFuncSetAttribute((const void*)caps_route_kernel<true>,
                            hipFuncAttributeMaxDynamicSharedMemorySize, (int)shmem);
        caps_route_kernel<true><<<(NB / 2) * OC, 1024, shmem, stream>>>(u, ws, ws + NW_DW, out);
    } else {
        hipFuncSetAttribute((const void*)caps_route_kernel<false>,
                            hipFuncAttributeMaxDynamicSharedMemorySize, (int)shmem);
        caps_route_kernel<false><<<(NB / 2) * OC, 1024, shmem, stream>>>(u, ws, ws + NW_DW, out);
    }
}